// Round 6
// baseline (70.645 us; speedup 1.0000x reference)
//
#include <hip/hip_runtime.h>

#define BATCH 512
#define NI 8192
#define NO 8192
#define BT 64     // batch tile (pinned per XCD)
#define NBT 8     // number of batch tiles = XCDs
#define CTB 16    // columns per block
#define CAP 96    // padded bucket capacity per column (Poisson(32), P(>96) ~ 1e-19)

typedef float fx4 __attribute__((ext_vector_type(4)));

__device__ __forceinline__ unsigned short f2bf(float f) {
    unsigned int u = __float_as_uint(f);
    u += 0x7FFFu + ((u >> 16) & 1u);
    return (unsigned short)(u >> 16);
}
__device__ __forceinline__ float bflo(unsigned int u) { return __uint_as_float(u << 16); }
__device__ __forceinline__ float bfhi(unsigned int u) { return __uint_as_float(u & 0xFFFF0000u); }

// ---- K1 (fused): blocks 0..1023 transpose x -> bf16 xTt[bt][NI][64];
//                  blocks 1024..1279 hist+scatter edges into padded buckets ----

__global__ __launch_bounds__(256) void prep_kernel(const float* __restrict__ x,
                                                   unsigned short* __restrict__ xTt,
                                                   const int* __restrict__ row,
                                                   const int* __restrict__ col,
                                                   const float* __restrict__ w,
                                                   int* __restrict__ counts,
                                                   unsigned int* __restrict__ sedgeP,
                                                   int nnz) {
    __shared__ float tile[64][65];
    int id = blockIdx.x;
    if (id < 1024) {
        int bx = id & 127;            // input-dim tile
        int by = id >> 7;             // batch tile (bt)
        int tx = threadIdx.x & 15;
        int ty = threadIdx.x >> 4;
#pragma unroll
        for (int k = 0; k < 4; ++k) {
            int b = by * 64 + ty + 16 * k;
            float4 v = *(const float4*)(x + (size_t)b * NI + bx * 64 + tx * 4);
            tile[ty + 16 * k][tx * 4 + 0] = v.x;
            tile[ty + 16 * k][tx * 4 + 1] = v.y;
            tile[ty + 16 * k][tx * 4 + 2] = v.z;
            tile[ty + 16 * k][tx * 4 + 3] = v.w;
        }
        __syncthreads();
#pragma unroll
        for (int k = 0; k < 4; ++k) {
            int rl = ty + 16 * k;
            int r = bx * 64 + rl;
            ushort4 v;
            v.x = f2bf(tile[tx * 4 + 0][rl]);
            v.y = f2bf(tile[tx * 4 + 1][rl]);
            v.z = f2bf(tile[tx * 4 + 2][rl]);
            v.w = f2bf(tile[tx * 4 + 3][rl]);
            *(ushort4*)(xTt + (size_t)by * NI * BT + (size_t)r * BT + tx * 4) = v;
        }
    } else {
        int e = ((id - 1024) * 256 + threadIdx.x) * 4;
        if (e + 3 < nnz) {
            int4 r = *(const int4*)(row + e);
            int4 c = *(const int4*)(col + e);
            float4 ww = *(const float4*)(w + e);
            int p;
            p = atomicAdd(&counts[c.x], 1);
            if (p < CAP) sedgeP[c.x * CAP + p] = (unsigned)(r.x & 0xFFFF) | ((unsigned)f2bf(ww.x) << 16);
            p = atomicAdd(&counts[c.y], 1);
            if (p < CAP) sedgeP[c.y * CAP + p] = (unsigned)(r.y & 0xFFFF) | ((unsigned)f2bf(ww.y) << 16);
            p = atomicAdd(&counts[c.z], 1);
            if (p < CAP) sedgeP[c.z * CAP + p] = (unsigned)(r.z & 0xFFFF) | ((unsigned)f2bf(ww.z) << 16);
            p = atomicAdd(&counts[c.w], 1);
            if (p < CAP) sedgeP[c.w * CAP + p] = (unsigned)(r.w & 0xFFFF) | ((unsigned)f2bf(ww.w) << 16);
        } else {
            for (; e < nnz; ++e) {
                int c = col[e];
                int p = atomicAdd(&counts[c], 1);
                if (p < CAP) sedgeP[c * CAP + p] = (unsigned)(row[e] & 0xFFFF) | ((unsigned)f2bf(w[e]) << 16);
            }
        }
    }
}

// ---- K2: main gather/accumulate (sedge staged in LDS, 32 gathers in flight/wave) ----

__global__ __launch_bounds__(256) void spmm_main_kernel(const unsigned short* __restrict__ xTt,
                                                        const unsigned int* __restrict__ sedgeP,
                                                        const int* __restrict__ counts,
                                                        const float* __restrict__ bias,
                                                        float* __restrict__ out) {
    __shared__ unsigned int ls[CTB * CAP];   // 6 KB of edge words for this block's 16 cols
    __shared__ int lcnt[CTB];
    __shared__ float tile[64 * 17];
    const int bt = blockIdx.x;               // 0..7 -> XCD via linear-id % 8
    const int wave = threadIdx.x >> 6;
    const int lane = threadIdx.x & 63;
    const int g = lane >> 4;                 // edge group 0..3
    const int i = lane & 15;                 // batch quad 0..15
    const int cb0 = blockIdx.y * CTB;
    const unsigned short* xb = xTt + (size_t)bt * NI * BT + i * 4;

    // stage this block's edge buckets (coalesced: 1536 consecutive dwords)
    for (int k = threadIdx.x; k < CTB * CAP; k += 256)
        ls[k] = sedgeP[(size_t)cb0 * CAP + k];
    if (threadIdx.x < CTB) {
        int c = counts[cb0 + threadIdx.x];
        lcnt[threadIdx.x] = c > CAP ? CAP : c;
    }
    __syncthreads();

    float4 res[4];
#pragma unroll
    for (int cc = 0; cc < 4; ++cc) {
        int colL = wave * 4 + cc;
        int cnt = lcnt[colL];
        const unsigned int* eb = ls + colL * CAP;
        float4 acc[8];
#pragma unroll
        for (int j = 0; j < 8; ++j) acc[j] = make_float4(0.f, 0.f, 0.f, 0.f);
        int e = g;
        // 32-edges-per-round tier: 8 independent gathers per group in flight
        for (; e + 28 < cnt; e += 32) {
            unsigned int p[8];
            uint2 q[8];
#pragma unroll
            for (int j = 0; j < 8; ++j) p[j] = eb[e + 4 * j];
#pragma unroll
            for (int j = 0; j < 8; ++j) q[j] = *(const uint2*)(xb + (size_t)(p[j] & 0xFFFFu) * BT);
#pragma unroll
            for (int j = 0; j < 8; ++j) {
                float ww = bfhi(p[j]);
                acc[j].x = fmaf(ww, bflo(q[j].x), acc[j].x);
                acc[j].y = fmaf(ww, bfhi(q[j].x), acc[j].y);
                acc[j].z = fmaf(ww, bflo(q[j].y), acc[j].z);
                acc[j].w = fmaf(ww, bfhi(q[j].y), acc[j].w);
            }
        }
        // 16-edge tier
        if (e + 12 < cnt) {
            unsigned int p[4];
            uint2 q[4];
#pragma unroll
            for (int j = 0; j < 4; ++j) p[j] = eb[e + 4 * j];
#pragma unroll
            for (int j = 0; j < 4; ++j) q[j] = *(const uint2*)(xb + (size_t)(p[j] & 0xFFFFu) * BT);
#pragma unroll
            for (int j = 0; j < 4; ++j) {
                float ww = bfhi(p[j]);
                acc[j].x = fmaf(ww, bflo(q[j].x), acc[j].x);
                acc[j].y = fmaf(ww, bfhi(q[j].x), acc[j].y);
                acc[j].z = fmaf(ww, bflo(q[j].y), acc[j].z);
                acc[j].w = fmaf(ww, bfhi(q[j].y), acc[j].w);
            }
            e += 16;
        }
        // tail
        for (; e < cnt; e += 4) {
            unsigned int p = eb[e];
            uint2 q = *(const uint2*)(xb + (size_t)(p & 0xFFFFu) * BT);
            float ww = bfhi(p);
            acc[0].x = fmaf(ww, bflo(q.x), acc[0].x);
            acc[0].y = fmaf(ww, bfhi(q.x), acc[0].y);
            acc[0].z = fmaf(ww, bflo(q.y), acc[0].z);
            acc[0].w = fmaf(ww, bfhi(q.y), acc[0].w);
        }
        float4 a0 = acc[0];
#pragma unroll
        for (int j = 1; j < 8; ++j) {
            a0.x += acc[j].x; a0.y += acc[j].y; a0.z += acc[j].z; a0.w += acc[j].w;
        }
        // reduce over the 4 edge groups (lanes xor 16, 32)
#pragma unroll
        for (int off = 16; off < 64; off <<= 1) {
            a0.x += __shfl_xor(a0.x, off, 64);
            a0.y += __shfl_xor(a0.y, off, 64);
            a0.z += __shfl_xor(a0.z, off, 64);
            a0.w += __shfl_xor(a0.w, off, 64);
        }
        res[cc] = a0;
    }

    // lane (i, g) owns column wave*4+g, batches i*4..+3 -> stage into LDS tile
    float4 r4 = (g == 0) ? res[0] : ((g == 1) ? res[1] : ((g == 2) ? res[2] : res[3]));
    int colL = wave * 4 + g;
    tile[(i * 4 + 0) * 17 + colL] = r4.x;
    tile[(i * 4 + 1) * 17 + colL] = r4.y;
    tile[(i * 4 + 2) * 17 + colL] = r4.z;
    tile[(i * 4 + 3) * 17 + colL] = r4.w;
    __syncthreads();

    // coalesced write-out (non-temporal: out is never read, skip RFO)
    int t = threadIdx.x;
    int r = t >> 2;
    int q = t & 3;
    float4 bb = *(const float4*)(bias + cb0 + q * 4);
    fx4 o;
    o.x = tile[r * 17 + q * 4 + 0] + bb.x;
    o.y = tile[r * 17 + q * 4 + 1] + bb.y;
    o.z = tile[r * 17 + q * 4 + 2] + bb.z;
    o.w = tile[r * 17 + q * 4 + 3] + bb.w;
    __builtin_nontemporal_store(o, (fx4*)(out + (size_t)(bt * BT + r) * NO + cb0 + q * 4));
}

// ---------------- launch ----------------

extern "C" void kernel_launch(void* const* d_in, const int* in_sizes, int n_in,
                              void* d_out, int out_size, void* d_ws, size_t ws_size,
                              hipStream_t stream) {
    const float* x    = (const float*)d_in[0];
    const float* w    = (const float*)d_in[1];
    const float* bias = (const float*)d_in[2];
    const int*   row  = (const int*)d_in[3];
    const int*   col  = (const int*)d_in[4];
    float* out = (float*)d_out;
    int nnz = in_sizes[1];

    char* ws = (char*)d_ws;
    size_t off = 0;
    unsigned short* xTt = (unsigned short*)(ws + off);
    off += (size_t)NI * BATCH * sizeof(unsigned short);            // 8 MB
    unsigned int* sedgeP = (unsigned int*)(ws + off);
    off += (size_t)NO * CAP * sizeof(unsigned int);                // 3 MB
    int* counts = (int*)(ws + off);
    off += (size_t)NO * sizeof(int);

    (void)hipMemsetAsync(counts, 0, (size_t)NO * sizeof(int), stream);
    int scatter_blocks = (nnz / 4 + 255) / 256;
    prep_kernel<<<1024 + scatter_blocks, 256, 0, stream>>>(x, xTt, row, col, w, counts, sedgeP, nnz);
    spmm_main_kernel<<<dim3(NBT, NO / CTB), 256, 0, stream>>>(xTt, sedgeP, counts, bias, out);
}